// Round 3
// baseline (269.463 us; speedup 1.0000x reference)
//
#include <hip/hip_runtime.h>

// x: (8, 320, 128, 128) fp32.  C=320 ≡ 0 mod 5  =>  plane%5 == channel%5.
// out(i,j) = (silu(x[s1]) + x[i,j]) * (sigmoid(silu(x[s2])) - 0.5)
// t=c%5: 0: s1=(i,j+1), s2=(i,j+2)   (mod 128, circular)
//        1: s1=(i,j-1), s2=(i,j-2)
//        2: s1=(i+1,j), s2=(i+2,j)
//        3: s1=(i-1,j), s2=(i-2,j)
//        4: s1=s2=(i,j)
//
// Layout facts: plane = 16384 floats = 4096 float4; row = 128 floats = 32
// float4 = 32 lanes. A 64-lane wave covers exactly 2 rows of one plane, so
// t is wave-uniform and W-shift neighbors live in adjacent lanes' registers.

#define PLANE_ELEMS 16384

// native vector type for nontemporal builtin (HIP float4 is a class -> rejected)
typedef float vfloat4 __attribute__((ext_vector_type(4)));

__device__ __forceinline__ float fast_sig(float z) {
    return __builtin_amdgcn_rcpf(1.0f + __expf(-z));
}
__device__ __forceinline__ float fast_silu(float z) {
    return z * fast_sig(z);
}

__global__ __launch_bounds__(256) void ablock_kernel(const float* __restrict__ x,
                                                     float* __restrict__ out,
                                                     int nv4) {
    int g = blockIdx.x * blockDim.x + threadIdx.x;   // float4 index
    if (g >= nv4) return;

    int plane = g >> 12;          // 4096 float4 per plane
    int o     = g & 4095;
    int row   = o >> 5;           // 32 float4 per row
    int c4    = o & 31;
    int lane  = threadIdx.x & 63;

    // wave-uniform type -> scalar branch (s_cbranch, no exec-mask churn)
    int t = __builtin_amdgcn_readfirstlane(plane) % 5;

    const float4* p4 = (const float4*)(x + (size_t)plane * PLANE_ELEMS);

    float4 x0 = p4[o];
    float4 x1, x2;

    if (t == 0) {            // +1/+2 along W: wrap elems from lane+1 (same 32-lane row)
        int src = (lane & 32) | ((lane + 1) & 31);
        float e4 = __shfl(x0.x, src);
        float e5 = __shfl(x0.y, src);
        x1 = make_float4(x0.y, x0.z, x0.w, e4);
        x2 = make_float4(x0.z, x0.w, e4, e5);
    } else if (t == 1) {     // -1/-2 along W: wrap elems from lane-1
        int src = (lane & 32) | ((lane + 31) & 31);
        float em1 = __shfl(x0.w, src);
        float em2 = __shfl(x0.z, src);
        x1 = make_float4(em1, x0.x, x0.y, x0.z);
        x2 = make_float4(em2, em1, x0.x, x0.y);
    } else if (t == 2) {     // +1/+2 along H: rows below (L1-resident re-reads)
        x1 = p4[(((row + 1) & 127) << 5) + c4];
        x2 = p4[(((row + 2) & 127) << 5) + c4];
    } else if (t == 3) {     // -1/-2 along H
        x1 = p4[(((row + 127) & 127) << 5) + c4];
        x2 = p4[(((row + 126) & 127) << 5) + c4];
    } else {                 // identity
        x1 = x0;
        x2 = x0;
    }

    vfloat4 r;
    r.x = (fast_silu(x1.x) + x0.x) * (fast_sig(fast_silu(x2.x)) - 0.5f);
    r.y = (fast_silu(x1.y) + x0.y) * (fast_sig(fast_silu(x2.y)) - 0.5f);
    r.z = (fast_silu(x1.z) + x0.z) * (fast_sig(fast_silu(x2.z)) - 0.5f);
    r.w = (fast_silu(x1.w) + x0.w) * (fast_sig(fast_silu(x2.w)) - 0.5f);

    // out is never re-read: bypass cache to keep L1/L2 for the H-shift halo
    __builtin_nontemporal_store(r, ((vfloat4*)out) + g);
}

extern "C" void kernel_launch(void* const* d_in, const int* in_sizes, int n_in,
                              void* d_out, int out_size, void* d_ws, size_t ws_size,
                              hipStream_t stream) {
    const float* x   = (const float*)d_in[0];
    float*       out = (float*)d_out;
    int n   = in_sizes[0];        // 41,943,040
    int nv4 = n >> 2;             // 10,485,760 float4
    int block = 256;
    int grid  = (nv4 + block - 1) / block;   // 40,960
    ablock_kernel<<<grid, block, 0, stream>>>(x, out, nv4);
}